// Round 5
// baseline (72.294 us; speedup 1.0000x reference)
//
#include <hip/hip_runtime.h>
#include <math.h>

// ---------------------------------------------------------------------------
// RegressionLoss: chamfer(32x32 shape pairs of 256 3D pts) -> softmax vs
// normalized-embedding inner-product softmax -> mean |p_hat - p|.
// Inputs: d_in[0] = embeddings (64x512 f32), d_in[1] = xyz (64x256x3 f32).
// Output: d_out[0] single f32.
//
// R5: G=2 chamfer blocks. R4 post-mortem: global uniform loads did NOT
// scalarize (broadcast VMEM, slower than LDS) -> revert to R3's LDS SoA
// broadcast, but amortize each ds_read_b128 over TWO outer shapes sharing
// one inner shape. Per inner c (32), the 31 outers = 15 G=2 groups + 1 G=1
// -> 16 blocks x 32 = 512 blocks = exactly 2/CU, perfect balance. Total
// LDS instrs halve (762K -> 393K). The 32 G=1 blocks (half VALU work)
// also compute the dots rows -- no extra blocks, no 3-block tail CUs.
// cdHalf[c*32+o] = mean_p min_q ||P_o[p]-P_c[q]||^2 (outer o -> inner c).
// ---------------------------------------------------------------------------

typedef float f32x2 __attribute__((ext_vector_type(2)));

__device__ __forceinline__ float waveReduceSum64(float v) {
    #pragma unroll
    for (int m = 32; m > 0; m >>= 1) v += __shfl_xor(v, m, 64);
    return v;
}

__global__ __launch_bounds__(256) void pairs_kernel(const float* __restrict__ emb,
                                                    const float* __restrict__ xyz,
                                                    float* __restrict__ cdHalf,
                                                    float* __restrict__ dots) {
    const int t = threadIdx.x;
    const int b = blockIdx.x;
    const int c = b >> 4;     // inner shape 0..31
    const int g = b & 15;     // group 0..15

    __shared__ __align__(16) float S[3 * 256];   // inner shape SoA: x,y,z (dots reuses)
    __shared__ float red0[4], red1[4];
    float* Sx = S;
    float* Sy = S + 256;
    float* Sz = S + 512;

    // outer-shape mapping: k in 0..30 -> o = k + (k>=c), skipping c
    const int k0 = 2 * g;
    const bool hasO1 = (g < 15);
    const int o0 = k0 + (k0 >= c ? 1 : 0);
    const int k1 = k0 + 1;
    const int o1 = hasO1 ? (k1 + (k1 >= c ? 1 : 0)) : o0;

    const float* Pc = xyz + (32 + c) * 768;      // shapes = xyz[32:]
    const float* P0 = xyz + (32 + o0) * 768;
    const float* P1 = xyz + (32 + o1) * 768;

    // stage inner shape c into LDS SoA
    Sx[t] = Pc[3*t]; Sy[t] = Pc[3*t+1]; Sz[t] = Pc[3*t+2];
    // my outer points (divergent, coalesced)
    const float p0x = P0[3*t], p0y = P0[3*t+1], p0z = P0[3*t+2];
    const float p1x = P1[3*t], p1y = P1[3*t+1], p1z = P1[3*t+2];
    __syncthreads();

    const f32x2 Ax = {p0x, p0x}, Ay = {p0y, p0y}, Az = {p0z, p0z};
    const f32x2 Bx = {p1x, p1x}, By = {p1y, p1y}, Bz = {p1z, p1z};

    float accA = 3.4e38f, accB = 3.4e38f;

    #pragma unroll 4
    for (int s = 0; s < 256; s += 4) {
        const float4 vx = *(const float4*)&Sx[s];   // broadcast b128
        const float4 vy = *(const float4*)&Sy[s];
        const float4 vz = *(const float4*)&Sz[s];
        {   // inner pts s, s+1
            const f32x2 qx = {vx.x, vx.y}, qy = {vy.x, vy.y}, qz = {vz.x, vz.y};
            f32x2 dx = Ax - qx, dy = Ay - qy, dz = Az - qz;
            f32x2 d = dx*dx + dy*dy + dz*dz;
            accA = fminf(accA, fminf(d.x, d.y));           // v_min3 bait
            f32x2 ex = Bx - qx, ey = By - qy, ez = Bz - qz;
            f32x2 e = ex*ex + ey*ey + ez*ez;
            accB = fminf(accB, fminf(e.x, e.y));
        }
        {   // inner pts s+2, s+3
            const f32x2 qx = {vx.z, vx.w}, qy = {vy.z, vy.w}, qz = {vz.z, vz.w};
            f32x2 dx = Ax - qx, dy = Ay - qy, dz = Az - qz;
            f32x2 d = dx*dx + dy*dy + dz*dz;
            accA = fminf(accA, fminf(d.x, d.y));
            f32x2 ex = Bx - qx, ey = By - qy, ez = Bz - qz;
            f32x2 e = ex*ex + ey*ey + ez*ez;
            accB = fminf(accB, fminf(e.x, e.y));
        }
    }

    float v0 = waveReduceSum64(accA);
    float v1 = waveReduceSum64(accB);
    if ((t & 63) == 0) { red0[t >> 6] = v0; red1[t >> 6] = v1; }
    __syncthreads();
    if (t == 0) {
        cdHalf[c * 32 + o0] = (red0[0] + red0[1] + red0[2] + red0[3]) * (1.0f / 256.0f);
        if (hasO1)
            cdHalf[c * 32 + o1] = (red1[0] + red1[1] + red1[2] + red1[3]) * (1.0f / 256.0f);
    }

    if (!hasO1) {
        // G=1 block (one per inner c): also compute dots row i=c.
        const int i = c;
        float* rowi = S;          // 512 floats
        const float* Ei = emb + i * 512;
        __syncthreads();          // everyone done reading S (chamfer loop)
        rowi[t]       = Ei[t];
        rowi[t + 256] = Ei[t + 256];
        __syncthreads();

        const int w    = t >> 6;
        const int lane = t & 63;

        float ni = 0.0f;
        #pragma unroll
        for (int m = 0; m < 8; ++m) { float a = rowi[lane + 64*m]; ni += a*a; }
        ni = waveReduceSum64(ni);

        for (int j = w; j < 32; j += 4) {
            const float* Ej = emb + (32 + j) * 512;
            float dot = 0.0f, nj = 0.0f;
            #pragma unroll
            for (int m = 0; m < 8; ++m) {
                float a  = rowi[lane + 64*m];
                float bv = Ej[lane + 64*m];
                dot += a * bv;
                nj  += bv * bv;
            }
            dot = waveReduceSum64(dot);
            nj  = waveReduceSum64(nj);
            if (lane == 0) dots[i * 32 + j] = dot * rsqrtf(ni * nj);
        }
    }
}

// 1 block x 1024 threads: assemble cd, softmaxes, mean abs diff
__global__ __launch_bounds__(1024) void finish_kernel(const float* __restrict__ cdHalf,
                                                      const float* __restrict__ dots,
                                                      float* __restrict__ out) {
    const int t = threadIdx.x;   // t = i*32 + j ; width-32 segments == rows
    const int i = t >> 5;
    const int j = t & 31;
    const float inv_denom = 1.0f / (2.0f * (0.997f / 3.0f) * (0.997f / 3.0f));

    float c = (i == j) ? 0.0f : (cdHalf[j * 32 + i] + cdHalf[i * 32 + j]);
    float s = -(c * c) * inv_denom;
    float h = dots[t];

    float m1 = s;
    #pragma unroll
    for (int k = 16; k > 0; k >>= 1) m1 = fmaxf(m1, __shfl_xor(m1, k, 32));
    float e1 = expf(s - m1);
    float sum1 = e1;
    #pragma unroll
    for (int k = 16; k > 0; k >>= 1) sum1 += __shfl_xor(sum1, k, 32);
    float p = e1 / sum1;

    float m2 = h;
    #pragma unroll
    for (int k = 16; k > 0; k >>= 1) m2 = fmaxf(m2, __shfl_xor(m2, k, 32));
    float e2 = expf(h - m2);
    float sum2 = e2;
    #pragma unroll
    for (int k = 16; k > 0; k >>= 1) sum2 += __shfl_xor(sum2, k, 32);
    float ph = e2 / sum2;

    float a = fabsf(ph - p);
    a = waveReduceSum64(a);

    __shared__ float red[16];
    if ((t & 63) == 0) red[t >> 6] = a;
    __syncthreads();
    if (t == 0) {
        float tot = 0.0f;
        #pragma unroll
        for (int k = 0; k < 16; ++k) tot += red[k];
        out[0] = tot * (1.0f / 1024.0f);
    }
}

extern "C" void kernel_launch(void* const* d_in, const int* in_sizes, int n_in,
                              void* d_out, int out_size, void* d_ws, size_t ws_size,
                              hipStream_t stream) {
    const float* emb = (const float*)d_in[0];   // 64 x 512
    const float* xyz = (const float*)d_in[1];   // 64 x 256 x 3
    float* cdHalf = (float*)d_ws;               // 32x32 directional halves
    float* dots   = cdHalf + 1024;              // 32x32
    float* out    = (float*)d_out;

    hipLaunchKernelGGL(pairs_kernel, dim3(512), dim3(256), 0, stream, emb, xyz, cdHalf, dots);
    hipLaunchKernelGGL(finish_kernel, dim3(1), dim3(1024), 0, stream, cdHalf, dots, out);
}